// Round 1
// baseline (529.948 us; speedup 1.0000x reference)
//
#include <hip/hip_runtime.h>
#include <cstdint>
#include <cstddef>

#define B_TOK 1024
#define DD_IN 3072
#define RHID 128
#define NEXP 8
#define EHID 2048
#define NCLS 10

typedef __attribute__((ext_vector_type(8))) short short8;
typedef __attribute__((ext_vector_type(4))) float floatx4;

// ---- helpers ------------------------------------------------------------
__device__ __forceinline__ unsigned short f2bf(float f) {
  unsigned u = __builtin_bit_cast(unsigned, f);
  u += 0x7fffu + ((u >> 16) & 1u);           // RNE
  return (unsigned short)(u >> 16);
}
__device__ __forceinline__ unsigned pk_bf16(float a, float b) {
  return (unsigned)f2bf(a) | ((unsigned)f2bf(b) << 16);
}
__device__ __forceinline__ float bf2f(unsigned short h) {
  unsigned u = ((unsigned)h) << 16;
  return __builtin_bit_cast(float, u);
}

// ---- out = eb2 broadcast (sum of normalized weights == 1, so eb2 added once)
__global__ __launch_bounds__(256) void k_init_out(float* out, const float* eb2) {
  int i = blockIdx.x * 256 + threadIdx.x;
  if (i < B_TOK * NCLS) out[i] = eb2[i % NCLS];
}

// ---- router GEMM1 (fp32, split-K S=16): partial[s][tok][hid] ------------
__global__ __launch_bounds__(256) void k_router_gemm(const float* __restrict__ x,
                                                     const float* __restrict__ rW1,
                                                     float* __restrict__ partial) {
  const int ttile = blockIdx.x;   // 16 tiles x 64 tokens
  const int s = blockIdx.y;       // 16 K-slices x 192
  const int T0 = ttile * 64;
  const int K0 = s * 192;
  __shared__ float xs[8][64];     // [k][tok]
  __shared__ float wsm[8][132];   // [k][hid], +4 pad
  float acc[4][8];
#pragma unroll
  for (int i = 0; i < 4; i++)
#pragma unroll
    for (int j = 0; j < 8; j++) acc[i][j] = 0.f;
  const int tx = threadIdx.x & 15, ty = threadIdx.x >> 4;
  for (int kc = K0; kc < K0 + 192; kc += 8) {
    __syncthreads();
    {
      int tok = threadIdx.x >> 2, kq = (threadIdx.x & 3) << 1;
      float2 v = *(const float2*)(x + (size_t)(T0 + tok) * DD_IN + kc + kq);
      xs[kq][tok] = v.x; xs[kq + 1][tok] = v.y;
    }
    {
      int k = threadIdx.x >> 5, n4 = (threadIdx.x & 31) << 2;
      *(float4*)&wsm[k][n4] = *(const float4*)(rW1 + (size_t)(kc + k) * RHID + n4);
    }
    __syncthreads();
#pragma unroll
    for (int kk = 0; kk < 8; kk++) {
      float wv[8], xv[4];
      *(float4*)&wv[0] = *(const float4*)&wsm[kk][tx * 8];
      *(float4*)&wv[4] = *(const float4*)&wsm[kk][tx * 8 + 4];
#pragma unroll
      for (int i = 0; i < 4; i++) xv[i] = xs[kk][ty * 4 + i];
#pragma unroll
      for (int i = 0; i < 4; i++)
#pragma unroll
        for (int j = 0; j < 8; j++) acc[i][j] += xv[i] * wv[j];
    }
  }
#pragma unroll
  for (int i = 0; i < 4; i++) {
    float* p = partial + ((size_t)s * B_TOK + T0 + ty * 4 + i) * RHID + tx * 8;
    *(float4*)p = *(float4*)&acc[i][0];
    *(float4*)(p + 4) = *(float4*)&acc[i][4];
  }
}

// ---- router finalize: reduce partials, relu, logits, top-2, bucket build
__global__ __launch_bounds__(256) void k_router_fin(const float* __restrict__ partial,
                                                    const float* __restrict__ rb1,
                                                    const float* __restrict__ rW2,
                                                    const float* __restrict__ rb2,
                                                    int* __restrict__ cnt,
                                                    int* __restrict__ tokL,
                                                    float* __restrict__ wtL) {
  const int lane = threadIdx.x & 63;
  const int tok = blockIdx.x * 4 + (threadIdx.x >> 6);
  float r0 = 0.f, r1 = 0.f;
  for (int s = 0; s < 16; s++) {
    const float* p = partial + ((size_t)s * B_TOK + tok) * RHID;
    r0 += p[lane]; r1 += p[lane + 64];
  }
  r0 = fmaxf(r0 + rb1[lane], 0.f);
  r1 = fmaxf(r1 + rb1[lane + 64], 0.f);
  float lg[8];
#pragma unroll
  for (int c = 0; c < 8; c++)
    lg[c] = r0 * rW2[lane * 8 + c] + r1 * rW2[(lane + 64) * 8 + c];
#pragma unroll
  for (int off = 32; off >= 1; off >>= 1)
#pragma unroll
    for (int c = 0; c < 8; c++) lg[c] += __shfl_down(lg[c], off);
  if (lane == 0) {
    float m1 = -1e30f, m2 = -1e30f; int i1 = 0, i2 = 0;
#pragma unroll
    for (int c = 0; c < 8; c++) {
      float l = lg[c] + rb2[c];
      if (l > m1) { m2 = m1; i2 = i1; m1 = l; i1 = c; }
      else if (l > m2) { m2 = l; i2 = c; }
    }
    // normalized top-2 softmax weights: w1 = e^l1/(e^l1+e^l2)
    float w1 = 1.f / (1.f + expf(m2 - m1));
    float w2 = 1.f - w1;
    int p1 = atomicAdd(&cnt[i1], 1);
    tokL[i1 * B_TOK + p1] = tok; wtL[i1 * B_TOK + p1] = w1;
    int p2 = atomicAdd(&cnt[i2], 1);
    tokL[i2 * B_TOK + p2] = tok; wtL[i2 * B_TOK + p2] = w2;
  }
}

// ---- expert kernel: gathered bf16 MFMA GEMM (layer1) + fused layer2+combine
// grid (nt=16 hid-chunks of 128, mt=8 token-tiles of 128, e=8 experts)
__global__ __launch_bounds__(256) void k_expert(const float* __restrict__ x,
                                                const float* __restrict__ eW1,
                                                const float* __restrict__ eb1,
                                                const float* __restrict__ eW2,
                                                const int* __restrict__ cnt,
                                                const int* __restrict__ tokL,
                                                const float* __restrict__ wtL,
                                                float* __restrict__ out) {
  const int nt = blockIdx.x;
  const int mt = blockIdx.y;
  const int e  = blockIdx.z;
  const int cnt_e = cnt[e];
  if (mt * 128 >= cnt_e) return;

  __shared__ union {
    struct { unsigned short As[128][72]; unsigned Bs[32][132]; } a;   // 18432+16896 B
    struct { unsigned short ehs[128][132]; float w2[128 * NCLS]; } b; // 33792+5120 B
  } u;
  __shared__ int stok[128];
  __shared__ float swt[128];

  const int tid = threadIdx.x;
  if (tid < 128) {
    int r = mt * 128 + tid;
    bool v = r < cnt_e;
    stok[tid] = v ? tokL[e * B_TOK + r] : -1;
    swt[tid]  = v ? wtL[e * B_TOK + r] : 0.f;
  }
  const int lane = tid & 63;
  const int wv = tid >> 6;
  const int wm = (wv & 1) * 64, wn = (wv >> 1) * 64;  // wave 64x64 subtile
  const int col = lane & 15, quad = lane >> 4;

  floatx4 acc[4][4];
#pragma unroll
  for (int mi = 0; mi < 4; mi++)
#pragma unroll
    for (int ni = 0; ni < 4; ni++) acc[mi][ni] = (floatx4)0.f;

  const float* W1e = eW1 + (size_t)e * DD_IN * EHID + (size_t)nt * 128;

  for (int k0 = 0; k0 < DD_IN; k0 += 64) {
    __syncthreads();
    // A stage: 128 tok x 64 k fp32 -> bf16, row stride 72 (pad 8)
#pragma unroll
    for (int i = 0; i < 8; i++) {
      int slot = tid + i * 256;
      int row = slot >> 4, c4 = (slot & 15) << 2;
      int tk = stok[row];
      float4 v = make_float4(0.f, 0.f, 0.f, 0.f);
      if (tk >= 0) v = *(const float4*)(x + (size_t)tk * DD_IN + k0 + c4);
      unsigned* dst = (unsigned*)&u.a.As[row][c4];
      dst[0] = pk_bf16(v.x, v.y);
      dst[1] = pk_bf16(v.z, v.w);
    }
    // B stage: eW1[k][n] -> pair-packed Bs[k/2][n] = (bf16 k, bf16 k+1)
#pragma unroll
    for (int i = 0; i < 4; i++) {
      int slot = tid + i * 256;
      int k2 = slot >> 5, n4 = (slot & 31) << 2;
      const float* src = W1e + (size_t)(k0 + k2 * 2) * EHID + n4;
      float4 va = *(const float4*)src;
      float4 vb = *(const float4*)(src + EHID);
      uint4 w;
      w.x = pk_bf16(va.x, vb.x); w.y = pk_bf16(va.y, vb.y);
      w.z = pk_bf16(va.z, vb.z); w.w = pk_bf16(va.w, vb.w);
      *(uint4*)&u.a.Bs[k2][n4] = w;
    }
    __syncthreads();
#pragma unroll
    for (int kk = 0; kk < 2; kk++) {
      short8 af[4], bf[4];
#pragma unroll
      for (int mi = 0; mi < 4; mi++)
        af[mi] = *(const short8*)&u.a.As[wm + mi * 16 + col][kk * 32 + quad * 8];
#pragma unroll
      for (int ni = 0; ni < 4; ni++) {
        int kb = kk * 16 + quad * 4;
        int nb = wn + ni * 16 + col;
        uint4 t;
        t.x = u.a.Bs[kb + 0][nb]; t.y = u.a.Bs[kb + 1][nb];
        t.z = u.a.Bs[kb + 2][nb]; t.w = u.a.Bs[kb + 3][nb];
        bf[ni] = __builtin_bit_cast(short8, t);
      }
#pragma unroll
      for (int mi = 0; mi < 4; mi++)
#pragma unroll
        for (int ni = 0; ni < 4; ni++)
          acc[mi][ni] = __builtin_amdgcn_mfma_f32_16x16x32_bf16(af[mi], bf[ni], acc[mi][ni], 0, 0, 0);
    }
  }
  __syncthreads();
  // epilogue: +eb1, relu, store eh (bf16) to LDS; C/D layout col=lane&15, row=quad*4+r
#pragma unroll
  for (int ni = 0; ni < 4; ni++) {
    int hid = wn + ni * 16 + col;
    float bias = eb1[(size_t)e * EHID + nt * 128 + hid];
#pragma unroll
    for (int mi = 0; mi < 4; mi++)
#pragma unroll
      for (int r = 0; r < 4; r++) {
        float val = fmaxf(acc[mi][ni][r] + bias, 0.f);
        u.b.ehs[wm + mi * 16 + quad * 4 + r][hid] = f2bf(val);
      }
  }
  // stage eW2 chunk (128 x 10)
#pragma unroll
  for (int i = 0; i < 5; i++) {
    int idx = tid + i * 256;
    if (idx < 128 * NCLS)
      u.b.w2[idx] = eW2[((size_t)e * EHID + nt * 128 + idx / NCLS) * NCLS + (idx % NCLS)];
  }
  __syncthreads();
  // layer2 partial: each thread handles (token, half of 128 hid)
  {
    int tok = tid >> 1, half = tid & 1;
    float a10[NCLS];
#pragma unroll
    for (int c = 0; c < NCLS; c++) a10[c] = 0.f;
    for (int hh = 0; hh < 64; hh++) {
      int h = half * 64 + hh;
      float eh = bf2f(u.b.ehs[tok][h]);
#pragma unroll
      for (int c = 0; c < NCLS; c++) a10[c] += eh * u.b.w2[h * NCLS + c];
    }
    int tk = stok[tok];
    if (tk >= 0) {
      float wt = swt[tok];
#pragma unroll
      for (int c = 0; c < NCLS; c++)
        atomicAdd(out + (size_t)tk * NCLS + c, wt * a10[c]);
    }
  }
}

// ---- launch -------------------------------------------------------------
extern "C" void kernel_launch(void* const* d_in, const int* in_sizes, int n_in,
                              void* d_out, int out_size, void* d_ws, size_t ws_size,
                              hipStream_t stream) {
  const float* x   = (const float*)d_in[0];
  const float* rW1 = (const float*)d_in[1];
  const float* rb1 = (const float*)d_in[2];
  const float* rW2 = (const float*)d_in[3];
  const float* rb2 = (const float*)d_in[4];
  const float* eW1 = (const float*)d_in[5];
  const float* eb1 = (const float*)d_in[6];
  const float* eW2 = (const float*)d_in[7];
  const float* eb2 = (const float*)d_in[8];
  float* out = (float*)d_out;

  char* ws = (char*)d_ws;
  int*   cnt     = (int*)(ws + 0);         // 8 ints (zeroed)
  int*   tokL    = (int*)(ws + 1024);      // 8*1024 int
  float* wtL     = (float*)(ws + 33792);   // 8*1024 float
  float* partial = (float*)(ws + 66560);   // 16*1024*128 float = 8 MB

  hipMemsetAsync(cnt, 0, 1024, stream);
  k_init_out<<<40, 256, 0, stream>>>(out, eb2);
  k_router_gemm<<<dim3(16, 16), 256, 0, stream>>>(x, rW1, partial);
  k_router_fin<<<256, 256, 0, stream>>>(partial, rb1, rW2, rb2, cnt, tokL, wtL);
  k_expert<<<dim3(16, 8, 8), 256, 0, stream>>>(x, eW1, eb1, eW2, cnt, tokL, wtL, out);
}

// Round 2
// 436.767 us; speedup vs baseline: 1.2133x; 1.2133x over previous
//
#include <hip/hip_runtime.h>
#include <cstdint>
#include <cstddef>

#define B_TOK 1024
#define DD_IN 3072
#define RHID 128
#define NEXP 8
#define EHID 2048
#define NCLS 10

typedef __attribute__((ext_vector_type(8))) short short8;
typedef __attribute__((ext_vector_type(4))) float floatx4;

// ---- helpers ------------------------------------------------------------
__device__ __forceinline__ unsigned short f2bf(float f) {
  unsigned u = __builtin_bit_cast(unsigned, f);
  u += 0x7fffu + ((u >> 16) & 1u);           // RNE
  return (unsigned short)(u >> 16);
}
__device__ __forceinline__ unsigned pk_bf16(float a, float b) {
  return (unsigned)f2bf(a) | ((unsigned)f2bf(b) << 16);
}
__device__ __forceinline__ float bf2f(unsigned short h) {
  unsigned u = ((unsigned)h) << 16;
  return __builtin_bit_cast(float, u);
}

// ---- router GEMM1 (fp32, split-K S=16): partial[s][tok][hid] ------------
// 16-deep K chunks (half the barriers) + register prefetch of next chunk.
__global__ __launch_bounds__(256) void k_router_gemm(const float* __restrict__ x,
                                                     const float* __restrict__ rW1,
                                                     float* __restrict__ partial) {
  const int ttile = blockIdx.x;   // 16 tiles x 64 tokens
  const int s = blockIdx.y;       // 16 K-slices x 192
  const int T0 = ttile * 64;
  const int K0 = s * 192;
  __shared__ float xs[16][64];     // [k][tok]
  __shared__ float wsm[16][132];   // [k][hid], +4 pad
  float acc[4][8];
#pragma unroll
  for (int i = 0; i < 4; i++)
#pragma unroll
    for (int j = 0; j < 8; j++) acc[i][j] = 0.f;
  const int tx = threadIdx.x & 15, ty = threadIdx.x >> 4;
  const int tid = threadIdx.x;

  const int xtok = tid >> 2, xk = (tid & 3) << 2;       // x loader coords
  const int wk0 = tid >> 5, wf0 = (tid & 31) << 2;      // rW1 loader (2 rounds)

  float4 pX, pW0, pW1;
  // prologue: load chunk 0
  pX  = *(const float4*)(x + (size_t)(T0 + xtok) * DD_IN + K0 + xk);
  pW0 = *(const float4*)(rW1 + (size_t)(K0 + wk0) * RHID + wf0);
  pW1 = *(const float4*)(rW1 + (size_t)(K0 + wk0 + 8) * RHID + wf0);

  for (int kc = K0; kc < K0 + 192; kc += 16) {
    // store staged regs -> LDS (transpose x)
    xs[xk + 0][xtok] = pX.x; xs[xk + 1][xtok] = pX.y;
    xs[xk + 2][xtok] = pX.z; xs[xk + 3][xtok] = pX.w;
    *(float4*)&wsm[wk0][wf0] = pW0;
    *(float4*)&wsm[wk0 + 8][wf0] = pW1;
    __syncthreads();
    if (kc + 16 < K0 + 192) {
      pX  = *(const float4*)(x + (size_t)(T0 + xtok) * DD_IN + kc + 16 + xk);
      pW0 = *(const float4*)(rW1 + (size_t)(kc + 16 + wk0) * RHID + wf0);
      pW1 = *(const float4*)(rW1 + (size_t)(kc + 16 + wk0 + 8) * RHID + wf0);
    }
#pragma unroll
    for (int kk = 0; kk < 16; kk++) {
      float wv[8], xv[4];
      *(float4*)&wv[0] = *(const float4*)&wsm[kk][tx * 8];
      *(float4*)&wv[4] = *(const float4*)&wsm[kk][tx * 8 + 4];
#pragma unroll
      for (int i = 0; i < 4; i++) xv[i] = xs[kk][ty * 4 + i];
#pragma unroll
      for (int i = 0; i < 4; i++)
#pragma unroll
        for (int j = 0; j < 8; j++) acc[i][j] += xv[i] * wv[j];
    }
    __syncthreads();
  }
#pragma unroll
  for (int i = 0; i < 4; i++) {
    float* p = partial + ((size_t)s * B_TOK + T0 + ty * 4 + i) * RHID + tx * 8;
    *(float4*)p = *(float4*)&acc[i][0];
    *(float4*)(p + 4) = *(float4*)&acc[i][4];
  }
}

// ---- router finalize: reduce partials, relu, logits, top-2, bucket build
// also initializes out = eb2 for its 4 tokens (sum of normalized weights == 1)
__global__ __launch_bounds__(256) void k_router_fin(const float* __restrict__ partial,
                                                    const float* __restrict__ rb1,
                                                    const float* __restrict__ rW2,
                                                    const float* __restrict__ rb2,
                                                    const float* __restrict__ eb2,
                                                    float* __restrict__ out,
                                                    int* __restrict__ cnt,
                                                    int* __restrict__ tokL,
                                                    float* __restrict__ wtL) {
  if (threadIdx.x < 4 * NCLS)
    out[blockIdx.x * 4 * NCLS + threadIdx.x] = eb2[threadIdx.x % NCLS];
  const int lane = threadIdx.x & 63;
  const int tok = blockIdx.x * 4 + (threadIdx.x >> 6);
  float r0 = 0.f, r1 = 0.f;
#pragma unroll
  for (int s = 0; s < 16; s++) {
    const float* p = partial + ((size_t)s * B_TOK + tok) * RHID;
    r0 += p[lane]; r1 += p[lane + 64];
  }
  r0 = fmaxf(r0 + rb1[lane], 0.f);
  r1 = fmaxf(r1 + rb1[lane + 64], 0.f);
  float lg[8];
#pragma unroll
  for (int c = 0; c < 8; c++)
    lg[c] = r0 * rW2[lane * 8 + c] + r1 * rW2[(lane + 64) * 8 + c];
#pragma unroll
  for (int off = 32; off >= 1; off >>= 1)
#pragma unroll
    for (int c = 0; c < 8; c++) lg[c] += __shfl_down(lg[c], off);
  if (lane == 0) {
    float m1 = -1e30f, m2 = -1e30f; int i1 = 0, i2 = 0;
#pragma unroll
    for (int c = 0; c < 8; c++) {
      float l = lg[c] + rb2[c];
      if (l > m1) { m2 = m1; i2 = i1; m1 = l; i1 = c; }
      else if (l > m2) { m2 = l; i2 = c; }
    }
    float w1 = 1.f / (1.f + expf(m2 - m1));
    float w2 = 1.f - w1;
    int p1 = atomicAdd(&cnt[i1], 1);
    tokL[i1 * B_TOK + p1] = tok; wtL[i1 * B_TOK + p1] = w1;
    int p2 = atomicAdd(&cnt[i2], 1);
    tokL[i2 * B_TOK + p2] = tok; wtL[i2 * B_TOK + p2] = w2;
  }
}

// ---- expert kernel: gathered bf16 MFMA GEMM (layer1) + fused layer2+combine
// grid (16 nt, 23 tiles): in-kernel scheduler walks cnt[] prefix to find
// (expert, tile) -> active blocks are contiguous ids, spread over all CUs.
__global__ __launch_bounds__(256, 2) void k_expert(const float* __restrict__ x,
                                                   const float* __restrict__ eW1,
                                                   const float* __restrict__ eb1,
                                                   const float* __restrict__ eW2,
                                                   const int* __restrict__ cnt,
                                                   const int* __restrict__ tokL,
                                                   const float* __restrict__ wtL,
                                                   float* __restrict__ out) {
  const int nt = blockIdx.x;
  // ---- scheduler: tile id -> (e, mt)
  int mt = blockIdx.y;
  int e = 0;
#pragma unroll
  for (e = 0; e < NEXP; e++) {
    int te = (cnt[e] + 127) >> 7;
    if (mt < te) break;
    mt -= te;
  }
  if (e >= NEXP) return;
  const int cnt_e = cnt[e];

  __shared__ union {
    struct { unsigned short As[128][72]; unsigned Bs[32][132]; } a;   // 18432+16896 B
    struct { unsigned short ehs[128][132]; float w2[128 * NCLS]; } b; // 33792+5120 B
  } u;
  __shared__ int stok[128];
  __shared__ float swt[128];

  const int tid = threadIdx.x;
  if (tid < 128) {
    int r = mt * 128 + tid;
    bool v = r < cnt_e;
    stok[tid] = v ? tokL[e * B_TOK + r] : -1;
    swt[tid]  = v ? wtL[e * B_TOK + r] : 0.f;
  }
  __syncthreads();   // stok visible before prologue loads

  const int lane = tid & 63;
  const int wv = tid >> 6;
  const int wm = (wv & 1) * 64, wn = (wv >> 1) * 64;  // wave 64x64 subtile
  const int col = lane & 15, quad = lane >> 4;

  floatx4 acc[4][4];
#pragma unroll
  for (int mi = 0; mi < 4; mi++)
#pragma unroll
    for (int ni = 0; ni < 4; ni++) acc[mi][ni] = (floatx4)0.f;

  const float* W1e = eW1 + (size_t)e * DD_IN * EHID + (size_t)nt * 128;

  // loader coords
  const int arow = tid >> 4, ac4 = (tid & 15) << 2;   // A: +16 rows per i
  const int bk2 = tid >> 5, bn4 = (tid & 31) << 2;    // B: +8 k2 per i

  float4 pA[8];
  float4 pBa[4], pBb[4];

  // ---- prologue: load K-chunk 0 into registers
#pragma unroll
  for (int i = 0; i < 8; i++) {
    int tk = stok[arow + i * 16];
    pA[i] = (tk >= 0) ? *(const float4*)(x + (size_t)tk * DD_IN + ac4)
                      : make_float4(0.f, 0.f, 0.f, 0.f);
  }
#pragma unroll
  for (int i = 0; i < 4; i++) {
    const float* src = W1e + (size_t)((bk2 + i * 8) * 2) * EHID + bn4;
    pBa[i] = *(const float4*)src;
    pBb[i] = *(const float4*)(src + EHID);
  }

  for (int k0 = 0; k0 < DD_IN; k0 += 64) {
    // ---- convert staged regs -> LDS
#pragma unroll
    for (int i = 0; i < 8; i++) {
      uint2 w;
      w.x = pk_bf16(pA[i].x, pA[i].y);
      w.y = pk_bf16(pA[i].z, pA[i].w);
      *(uint2*)&u.a.As[arow + i * 16][ac4] = w;
    }
#pragma unroll
    for (int i = 0; i < 4; i++) {
      uint4 w;
      w.x = pk_bf16(pBa[i].x, pBb[i].x); w.y = pk_bf16(pBa[i].y, pBb[i].y);
      w.z = pk_bf16(pBa[i].z, pBb[i].z); w.w = pk_bf16(pBa[i].w, pBb[i].w);
      *(uint4*)&u.a.Bs[bk2 + i * 8][bn4] = w;
    }
    __syncthreads();
    // ---- issue next chunk's loads (overlap with MFMA below)
    if (k0 + 64 < DD_IN) {
#pragma unroll
      for (int i = 0; i < 8; i++) {
        int tk = stok[arow + i * 16];
        pA[i] = (tk >= 0) ? *(const float4*)(x + (size_t)tk * DD_IN + k0 + 64 + ac4)
                          : make_float4(0.f, 0.f, 0.f, 0.f);
      }
#pragma unroll
      for (int i = 0; i < 4; i++) {
        const float* src = W1e + (size_t)(k0 + 64 + (bk2 + i * 8) * 2) * EHID + bn4;
        pBa[i] = *(const float4*)src;
        pBb[i] = *(const float4*)(src + EHID);
      }
    }
    // ---- MFMA on LDS tile
#pragma unroll
    for (int kk = 0; kk < 2; kk++) {
      short8 af[4], bf[4];
#pragma unroll
      for (int mi = 0; mi < 4; mi++)
        af[mi] = *(const short8*)&u.a.As[wm + mi * 16 + col][kk * 32 + quad * 8];
#pragma unroll
      for (int ni = 0; ni < 4; ni++) {
        int kb = kk * 16 + quad * 4;
        int nb = wn + ni * 16 + col;
        uint4 t;
        t.x = u.a.Bs[kb + 0][nb]; t.y = u.a.Bs[kb + 1][nb];
        t.z = u.a.Bs[kb + 2][nb]; t.w = u.a.Bs[kb + 3][nb];
        bf[ni] = __builtin_bit_cast(short8, t);
      }
#pragma unroll
      for (int mi = 0; mi < 4; mi++)
#pragma unroll
        for (int ni = 0; ni < 4; ni++)
          acc[mi][ni] = __builtin_amdgcn_mfma_f32_16x16x32_bf16(af[mi], bf[ni], acc[mi][ni], 0, 0, 0);
    }
    __syncthreads();
  }
  // epilogue: +eb1, relu, store eh (bf16) to LDS; C/D layout col=lane&15, row=quad*4+r
#pragma unroll
  for (int ni = 0; ni < 4; ni++) {
    int hid = wn + ni * 16 + col;
    float bias = eb1[(size_t)e * EHID + nt * 128 + hid];
#pragma unroll
    for (int mi = 0; mi < 4; mi++)
#pragma unroll
      for (int r = 0; r < 4; r++) {
        float val = fmaxf(acc[mi][ni][r] + bias, 0.f);
        u.b.ehs[wm + mi * 16 + quad * 4 + r][hid] = f2bf(val);
      }
  }
  // stage eW2 chunk (128 x 10)
#pragma unroll
  for (int i = 0; i < 5; i++) {
    int idx = tid + i * 256;
    if (idx < 128 * NCLS)
      u.b.w2[idx] = eW2[((size_t)e * EHID + nt * 128 + idx / NCLS) * NCLS + (idx % NCLS)];
  }
  __syncthreads();
  // layer2 partial: each thread handles (token, half of 128 hid)
  {
    int tok = tid >> 1, half = tid & 1;
    float a10[NCLS];
#pragma unroll
    for (int c = 0; c < NCLS; c++) a10[c] = 0.f;
    for (int hh = 0; hh < 64; hh++) {
      int h = half * 64 + hh;
      float eh = bf2f(u.b.ehs[tok][h]);
#pragma unroll
      for (int c = 0; c < NCLS; c++) a10[c] += eh * u.b.w2[h * NCLS + c];
    }
    int tk = stok[tok];
    if (tk >= 0) {
      float wt = swt[tok];
#pragma unroll
      for (int c = 0; c < NCLS; c++)
        atomicAdd(out + (size_t)tk * NCLS + c, wt * a10[c]);
    }
  }
}

// ---- launch -------------------------------------------------------------
extern "C" void kernel_launch(void* const* d_in, const int* in_sizes, int n_in,
                              void* d_out, int out_size, void* d_ws, size_t ws_size,
                              hipStream_t stream) {
  const float* x   = (const float*)d_in[0];
  const float* rW1 = (const float*)d_in[1];
  const float* rb1 = (const float*)d_in[2];
  const float* rW2 = (const float*)d_in[3];
  const float* rb2 = (const float*)d_in[4];
  const float* eW1 = (const float*)d_in[5];
  const float* eb1 = (const float*)d_in[6];
  const float* eW2 = (const float*)d_in[7];
  const float* eb2 = (const float*)d_in[8];
  float* out = (float*)d_out;

  char* ws = (char*)d_ws;
  int*   cnt     = (int*)(ws + 0);         // 8 ints (zeroed)
  int*   tokL    = (int*)(ws + 1024);      // 8*1024 int
  float* wtL     = (float*)(ws + 33792);   // 8*1024 float
  float* partial = (float*)(ws + 66560);   // 16*1024*128 float = 8 MB

  hipMemsetAsync(cnt, 0, 1024, stream);
  k_router_gemm<<<dim3(16, 16), 256, 0, stream>>>(x, rW1, partial);
  k_router_fin<<<256, 256, 0, stream>>>(partial, rb1, rW2, rb2, eb2, out, cnt, tokL, wtL);
  k_expert<<<dim3(16, 23), 256, 0, stream>>>(x, eW1, eb1, eW2, cnt, tokL, wtL, out);
}